// Round 13
// baseline (177.616 us; speedup 1.0000x reference)
//
#include <hip/hip_runtime.h>
#include <hip/hip_bf16.h>

#define B_    8
#define N_    2048
#define DIN_  512
#define DOUT_ 256
#define NBUCK 20

typedef __attribute__((ext_vector_type(8))) short  short8;
typedef __attribute__((ext_vector_type(4))) float  floatx4;

__device__ __forceinline__ unsigned short f2b(float f) {
    __hip_bfloat16 h = __float2bfloat16(f);
    unsigned short u;
    __builtin_memcpy(&u, &h, 2);
    return u;
}

__device__ __forceinline__ void load_lds16(const unsigned short* g, unsigned short* l) {
    __builtin_amdgcn_global_load_lds(
        (const __attribute__((address_space(1))) unsigned int*)g,
        (__attribute__((address_space(3))) unsigned int*)l, 16, 0, 0);
}

// ---------------- fused prep: Wq,Wk -> bf16  +  wvs = Wv^T.Ws, bvs = bv.Ws ----
__global__ __launch_bounds__(256) void prep_kernel(
    const float* __restrict__ wq, const float* __restrict__ wk,
    const float* __restrict__ Wv, const float* __restrict__ Ws,
    const float* __restrict__ bv,
    unsigned short* __restrict__ dst, float* __restrict__ wvs,
    float* __restrict__ bvs) {
    const int blk = blockIdx.x, tid = threadIdx.x;
    if (blk < 128) {
        int i = (blk * 256 + tid) * 8;  // 0 .. 262144-8
        const float* src = (i < 131072) ? (wq + i) : (wk + (i - 131072));
        float4 a = *(const float4*)(src);
        float4 b = *(const float4*)(src + 4);
        uint4 r;
        r.x = f2b(a.x) | ((unsigned)f2b(a.y) << 16);
        r.y = f2b(a.z) | ((unsigned)f2b(a.w) << 16);
        r.z = f2b(b.x) | ((unsigned)f2b(b.y) << 16);
        r.w = f2b(b.z) | ((unsigned)f2b(b.w) << 16);
        *(uint4*)(dst + i) = r;
    } else {
        __shared__ float wsl[DOUT_];
        wsl[tid] = Ws[tid];
        __syncthreads();
        if (tid < 128) {
            int d = (blk - 128) * 128 + tid;
            float s = 0.f;
#pragma unroll 8
            for (int o = 0; o < DOUT_; ++o) s += Wv[(size_t)o * DIN_ + d] * wsl[o];
            wvs[d] = s;
        }
        if (blk == 128 && tid < 64) {
            float bb = wsl[tid] * bv[tid] + wsl[tid + 64] * bv[tid + 64] +
                       wsl[tid + 128] * bv[tid + 128] + wsl[tid + 192] * bv[tid + 192];
            for (int off = 1; off < 64; off <<= 1) bb += __shfl_xor(bb, off, 64);
            if (tid == 0) *bvs = bb;
        }
    }
}

// ---------------- x -> bf16, fused vw = x . wvs + bvs ----------------
__global__ __launch_bounds__(256) void cvt_x_kernel(const float* __restrict__ x,
                                                    const float* __restrict__ wvs,
                                                    const float* __restrict__ bvs,
                                                    unsigned short* __restrict__ xb,
                                                    float* __restrict__ vw) {
    int tid = threadIdx.x, wave = tid >> 6, lane = tid & 63;
    int row = blockIdx.x * 4 + wave;
    size_t base = (size_t)row * DIN_ + lane * 8;
    float4 a = *(const float4*)(x + base);
    float4 b = *(const float4*)(x + base + 4);
    float4 wa = *(const float4*)(wvs + lane * 8);
    float4 wb = *(const float4*)(wvs + lane * 8 + 4);
    uint4 r;
    r.x = f2b(a.x) | ((unsigned)f2b(a.y) << 16);
    r.y = f2b(a.z) | ((unsigned)f2b(a.w) << 16);
    r.z = f2b(b.x) | ((unsigned)f2b(b.y) << 16);
    r.w = f2b(b.z) | ((unsigned)f2b(b.w) << 16);
    *(uint4*)(xb + base) = r;
    float d = a.x * wa.x + a.y * wa.y + a.z * wa.z + a.w * wa.w +
              b.x * wb.x + b.y * wb.y + b.z * wb.z + b.w * wb.w;
    for (int off = 1; off < 64; off <<= 1) d += __shfl_xor(d, off, 64);
    if (lane == 0) vw[row] = d + *bvs;  // bvs folded in HERE (only here)
}

// ---------------- Q,K GEMM — m97-style 128x128 LDS-staged tiles (r10) --------
__global__ __launch_bounds__(256, 2) void qkv_kernel(
    const unsigned short* __restrict__ xb, const unsigned short* __restrict__ wb,
    const float* __restrict__ bq, const float* __restrict__ bk,
    unsigned short* __restrict__ qo, unsigned short* __restrict__ ko) {
    __shared__ unsigned short alds[128 * 32];  // 8 KB
    __shared__ unsigned short blds[128 * 32];  // 8 KB
    const int g = blockIdx.x;
    const int xcd = g & 7, t2 = g >> 3;
    const int colBlk = t2 & 3, rowGrp = t2 >> 2;
    const int rowBlk = rowGrp * 8 + xcd;
    const int tid = threadIdx.x;
    const int wave = tid >> 6, lane = tid & 63, quad = lane >> 4, l16 = lane & 15;
    const int wr = wave >> 1, wc = wave & 1;
    const int row0 = rowBlk * 128, col0 = colBlk * 128;

    floatx4 acc[4][4];
#pragma unroll
    for (int i = 0; i < 4; ++i)
#pragma unroll
        for (int j = 0; j < 4; ++j) acc[i][j] = (floatx4){0.f, 0.f, 0.f, 0.f};

    const unsigned short* ag = xb + (size_t)(row0 + (tid >> 2)) * DIN_ + (tid & 3) * 8;
    const unsigned short* bg = wb + (size_t)(col0 + (tid >> 2)) * DIN_ + (tid & 3) * 8;
    unsigned short* alw0 = alds + (size_t)(wave * 64) * 8;
    unsigned short* alw1 = alds + (size_t)(256 + wave * 64) * 8;
    unsigned short* blw0 = blds + (size_t)(wave * 64) * 8;
    unsigned short* blw1 = blds + (size_t)(256 + wave * 64) * 8;

#pragma unroll 1
    for (int kc = 0; kc < DIN_; kc += 32) {
        __syncthreads();
        load_lds16(ag + kc, alw0);
        load_lds16(ag + (size_t)64 * DIN_ + kc, alw1);
        load_lds16(bg + kc, blw0);
        load_lds16(bg + (size_t)64 * DIN_ + kc, blw1);
        __syncthreads();
        short8 af[4], bf[4];
#pragma unroll
        for (int f = 0; f < 4; ++f) {
            af[f] = *(const short8*)&alds[(size_t)(wr * 64 + f * 16 + l16) * 32 + quad * 8];
            bf[f] = *(const short8*)&blds[(size_t)(wc * 64 + f * 16 + l16) * 32 + quad * 8];
        }
#pragma unroll
        for (int i = 0; i < 4; ++i)
#pragma unroll
            for (int j = 0; j < 4; ++j)
                acc[i][j] = __builtin_amdgcn_mfma_f32_16x16x32_bf16(af[i], bf[j], acc[i][j], 0, 0, 0);
    }

#pragma unroll
    for (int j = 0; j < 4; ++j) {
        int col = col0 + wc * 64 + j * 16 + l16;
        unsigned short* dst = (col < 256) ? qo : ko;
        float bias = (col < 256) ? bq[col] : bk[col - 256];
        int c = col & 255;
#pragma unroll
        for (int i = 0; i < 4; ++i)
#pragma unroll
            for (int r = 0; r < 4; ++r) {
                int row = row0 + wr * 64 + i * 16 + quad * 4 + r;
                dst[(size_t)row * DOUT_ + c] = f2b(acc[i][j][r] + bias);
            }
    }
}

// ---------------- gated flash attention — barrier-free pipeline, r11+trims ---
// grid 256: b = g&7 (XCD-affine), rblk = g>>3 -> 64 q-rows/block, 8 waves.
// r11/r12 lesson: register file pins waves/SIMD x K-reuse ~= 8, so occupancy
// can't be raised without losing reuse. This round keeps r11's best point
// (64 rows, reuse 4, 2 waves/SIMD) and cuts per-chunk VALU overhead instead
// (~3/4 of measured VALU was address math, not exp):
//  - 8 DMA source pointers hoisted to registers, bumped by the constant
//    64KB chunk stride (was ~60 VALU of row/XOR math per chunk).
//  - chunk loop unrolled x2 so dbuf parity (bufc/bufn) and all LDS
//    addresses are compile-time. No K-data hoisted to registers (r5 spill
//    lesson does not apply; DMA lands in LDS). WRITE_SIZE = spill detector.
//  - 0.2 factor folded into prn5/prm5 (one mul per chunk, not per element).
__global__ __launch_bounds__(512, 2) void attn_kernel(
    const unsigned short* __restrict__ q, const unsigned short* __restrict__ k,
    const float* __restrict__ vw, const int* __restrict__ pr,
    const float* __restrict__ rank_emb, const float* __restrict__ rank_w,
    const float* __restrict__ bs, float* __restrict__ out) {
    const int g = blockIdx.x;
    const int b = g & 7, rblk = g >> 3;
    const int tid = threadIdx.x, wave = tid >> 6, lane = tid & 63;
    const int quad = lane >> 4, l16 = lane & 15;
    const int n0 = rblk * 64;
    const int sw = l16 & 7;

    __shared__ unsigned short klds[2][8][4096];  // [parity][wave][8KB]
    __shared__ float gtab[NBUCK];
    __shared__ float lL[8][64], wdL[8][64];

    if (tid < NBUCK)  // scale * log2e folded in
        gtab[tid] = 0.0625f * 1.44269504f / (1.f + __expf(-rank_w[0] * rank_emb[tid]));
    __syncthreads();  // gtab visibility — the only pre-loop barrier

    const unsigned short* qb = q + (size_t)b * N_ * DOUT_;
    const unsigned short* kb = k + (size_t)b * N_ * DOUT_;
    const float* vwb = vw + b * N_;
    const int* prb = pr + b * N_;

    short8 qf[4][8];
#pragma unroll
    for (int a = 0; a < 4; ++a)
#pragma unroll
        for (int c = 0; c < 8; ++c)
            qf[a][c] = *(const short8*)(qb + (size_t)(n0 + a * 16 + l16) * DOUT_ + c * 32 + quad * 8);

    float prn5[4][4];
#pragma unroll
    for (int a = 0; a < 4; ++a)
#pragma unroll
        for (int r = 0; r < 4; ++r)
            prn5[a][r] = (float)prb[n0 + a * 16 + quad * 4 + r] * 0.2f;

    float lacc[4][4], wacc[4][4];
#pragma unroll
    for (int a = 0; a < 4; ++a)
#pragma unroll
        for (int r = 0; r < 4; ++r) { lacc[a][r] = 0.f; wacc[a][r] = 0.f; }

    // hoisted DMA source pointers (chunk stride = 128*DOUT_ elems = 64KB)
    const unsigned short* kwb = kb + (size_t)(wave * 16) * DOUT_;
    const int srow = lane >> 5;
    const int spos = lane & 31;
    const unsigned short* srcp[8];
#pragma unroll
    for (int i = 0; i < 8; ++i) {
        int row = i * 2 + srow;
        int gseg = spos ^ (row & 7);
        srcp[i] = kwb + (size_t)row * DOUT_ + gseg * 8;
    }
    unsigned short* buf0 = &klds[0][wave][0];
    unsigned short* buf1 = &klds[1][wave][0];

    // prologue: stage chunk 0 into buf0
#pragma unroll
    for (int i = 0; i < 8; ++i) {
        load_lds16(srcp[i], buf0 + i * 512);
        srcp[i] += 128 * DOUT_;
    }

#pragma unroll 2
    for (int j = 0; j < 16; ++j) {
        unsigned short* bufc = (j & 1) ? buf1 : buf0;
        unsigned short* bufn = (j & 1) ? buf0 : buf1;

        // ---- fragment reads + MFMA (vmcnt wait on THIS wave's chunk-j DMA) --
        floatx4 s[4];
#pragma unroll
        for (int a = 0; a < 4; ++a) s[a] = (floatx4){0.f, 0.f, 0.f, 0.f};
#pragma unroll
        for (int c = 0; c < 8; ++c) {
            int seg = (quad + 4 * c) ^ sw;
            short8 kf = *(const short8*)&bufc[((size_t)l16 * 32 + seg) * 8];
            s[0] = __builtin_amdgcn_mfma_f32_16x16x32_bf16(qf[0][c], kf, s[0], 0, 0, 0);
            s[1] = __builtin_amdgcn_mfma_f32_16x16x32_bf16(qf[1][c], kf, s[1], 0, 0, 0);
            s[2] = __builtin_amdgcn_mfma_f32_16x16x32_bf16(qf[2][c], kf, s[2], 0, 0, 0);
            s[3] = __builtin_amdgcn_mfma_f32_16x16x32_bf16(qf[3][c], kf, s[3], 0, 0, 0);
        }
        // ---- prefetch chunk j+1 (pointer-bump only; overlaps exp below) -----
        if (j < 15) {
#pragma unroll
            for (int i = 0; i < 8; ++i) {
                load_lds16(srcp[i], bufn + i * 512);
                srcp[i] += 128 * DOUT_;
            }
        }
        int colw = j * 128 + wave * 16 + l16;
        float prm5 = (float)prb[colw] * 0.2f;
        float vwv = vwb[colw];
        // ---- gate + exp accumulation ----------------------------------------
#pragma unroll
        for (int a = 0; a < 4; ++a)
#pragma unroll
            for (int r = 0; r < 4; ++r) {
                float d5 = fabsf(prn5[a][r] - prm5);
                int idx = (int)fminf(d5, 19.0f);
                float p = exp2f(s[a][r] * gtab[idx]);
                lacc[a][r] += p;
                wacc[a][r] += p * vwv;
            }
    }

    // merge partial (l, wd) across the 16 column-lanes
#pragma unroll
    for (int off = 1; off < 16; off <<= 1) {
#pragma unroll
        for (int a = 0; a < 4; ++a)
#pragma unroll
            for (int r = 0; r < 4; ++r) {
                lacc[a][r] += __shfl_xor(lacc[a][r], off, 64);
                wacc[a][r] += __shfl_xor(wacc[a][r], off, 64);
            }
    }
    if (l16 == 0) {
#pragma unroll
        for (int a = 0; a < 4; ++a)
#pragma unroll
            for (int r = 0; r < 4; ++r) {
                int row = a * 16 + quad * 4 + r;
                lL[wave][row]  = lacc[a][r];
                wdL[wave][row] = wacc[a][r];
            }
    }
    __syncthreads();
    if (tid < 64) {
        float l = 0.f, wd = 0.f;
#pragma unroll
        for (int s2 = 0; s2 < 8; ++s2) { l += lL[s2][tid]; wd += wdL[s2][tid]; }
        float logit = wd / l + bs[0];   // bvs already inside vw
        out[(size_t)b * N_ + n0 + tid] = 1.f / (1.f + __expf(-logit));
    }
}

// ---------------- launch ----------------
extern "C" void kernel_launch(void* const* d_in, const int* in_sizes, int n_in,
                              void* d_out, int out_size, void* d_ws, size_t ws_size,
                              hipStream_t stream) {
    const float* x   = (const float*)d_in[0];
    const int*   pr  = (const int*)d_in[1];
    const float* Wq  = (const float*)d_in[2];
    const float* bq  = (const float*)d_in[3];
    const float* Wk  = (const float*)d_in[4];
    const float* bk  = (const float*)d_in[5];
    const float* Wv  = (const float*)d_in[6];
    const float* bv  = (const float*)d_in[7];
    const float* Ws  = (const float*)d_in[8];
    const float* bs  = (const float*)d_in[9];
    const float* remb = (const float*)d_in[10];
    const float* rw   = (const float*)d_in[11];
    float* out = (float*)d_out;

    char* ws = (char*)d_ws;
    unsigned short* xb  = (unsigned short*)ws;                    // 16,777,216 B
    unsigned short* wb  = (unsigned short*)(ws + 16777216);       //    524,288 B
    unsigned short* q   = (unsigned short*)(ws + 17301504);       //  8,388,608 B
    unsigned short* kk  = (unsigned short*)(ws + 25690112);       //  8,388,608 B
    float*          vwp = (float*)(ws + 34078720);                //     65,536 B
    float*          wvs = (float*)(ws + 34144256);                //      2,048 B
    float*          bvs = (float*)(ws + 34146304);                //          4 B

    hipLaunchKernelGGL(prep_kernel, dim3(132), dim3(256), 0, stream,
                       Wq, Wk, Wv, Ws, bv, wb, wvs, bvs);
    hipLaunchKernelGGL(cvt_x_kernel, dim3(4096), dim3(256), 0, stream, x, wvs, bvs, xb, vwp);
    hipLaunchKernelGGL(qkv_kernel, dim3(512), dim3(256), 0, stream,
                       xb, wb, bq, bk, q, kk);
    hipLaunchKernelGGL(attn_kernel, dim3(256), dim3(512), 0, stream,
                       q, kk, vwp, pr, remb, rw, bs, out);
}

// Round 14
// 159.524 us; speedup vs baseline: 1.1134x; 1.1134x over previous
//
#include <hip/hip_runtime.h>
#include <hip/hip_bf16.h>

#define B_    8
#define N_    2048
#define DIN_  512
#define DOUT_ 256
#define NBUCK 20

typedef __attribute__((ext_vector_type(8))) short  short8;
typedef __attribute__((ext_vector_type(4))) float  floatx4;

__device__ __forceinline__ unsigned short f2b(float f) {
    __hip_bfloat16 h = __float2bfloat16(f);
    unsigned short u;
    __builtin_memcpy(&u, &h, 2);
    return u;
}

__device__ __forceinline__ void load_lds16(const unsigned short* g, unsigned short* l) {
    __builtin_amdgcn_global_load_lds(
        (const __attribute__((address_space(1))) unsigned int*)g,
        (__attribute__((address_space(3))) unsigned int*)l, 16, 0, 0);
}

// ---------------- fused prep: Wq,Wk -> bf16  +  wvs = Wv^T.Ws, bvs = bv.Ws ----
__global__ __launch_bounds__(256) void prep_kernel(
    const float* __restrict__ wq, const float* __restrict__ wk,
    const float* __restrict__ Wv, const float* __restrict__ Ws,
    const float* __restrict__ bv,
    unsigned short* __restrict__ dst, float* __restrict__ wvs,
    float* __restrict__ bvs) {
    const int blk = blockIdx.x, tid = threadIdx.x;
    if (blk < 128) {
        int i = (blk * 256 + tid) * 8;  // 0 .. 262144-8
        const float* src = (i < 131072) ? (wq + i) : (wk + (i - 131072));
        float4 a = *(const float4*)(src);
        float4 b = *(const float4*)(src + 4);
        uint4 r;
        r.x = f2b(a.x) | ((unsigned)f2b(a.y) << 16);
        r.y = f2b(a.z) | ((unsigned)f2b(a.w) << 16);
        r.z = f2b(b.x) | ((unsigned)f2b(b.y) << 16);
        r.w = f2b(b.z) | ((unsigned)f2b(b.w) << 16);
        *(uint4*)(dst + i) = r;
    } else {
        __shared__ float wsl[DOUT_];
        wsl[tid] = Ws[tid];
        __syncthreads();
        if (tid < 128) {
            int d = (blk - 128) * 128 + tid;
            float s = 0.f;
#pragma unroll 8
            for (int o = 0; o < DOUT_; ++o) s += Wv[(size_t)o * DIN_ + d] * wsl[o];
            wvs[d] = s;
        }
        if (blk == 128 && tid < 64) {
            float bb = wsl[tid] * bv[tid] + wsl[tid + 64] * bv[tid + 64] +
                       wsl[tid + 128] * bv[tid + 128] + wsl[tid + 192] * bv[tid + 192];
            for (int off = 1; off < 64; off <<= 1) bb += __shfl_xor(bb, off, 64);
            if (tid == 0) *bvs = bb;
        }
    }
}

// ---------------- x -> bf16, fused vw = x . wvs + bvs ----------------
__global__ __launch_bounds__(256) void cvt_x_kernel(const float* __restrict__ x,
                                                    const float* __restrict__ wvs,
                                                    const float* __restrict__ bvs,
                                                    unsigned short* __restrict__ xb,
                                                    float* __restrict__ vw) {
    int tid = threadIdx.x, wave = tid >> 6, lane = tid & 63;
    int row = blockIdx.x * 4 + wave;
    size_t base = (size_t)row * DIN_ + lane * 8;
    float4 a = *(const float4*)(x + base);
    float4 b = *(const float4*)(x + base + 4);
    float4 wa = *(const float4*)(wvs + lane * 8);
    float4 wb = *(const float4*)(wvs + lane * 8 + 4);
    uint4 r;
    r.x = f2b(a.x) | ((unsigned)f2b(a.y) << 16);
    r.y = f2b(a.z) | ((unsigned)f2b(a.w) << 16);
    r.z = f2b(b.x) | ((unsigned)f2b(b.y) << 16);
    r.w = f2b(b.z) | ((unsigned)f2b(b.w) << 16);
    *(uint4*)(xb + base) = r;
    float d = a.x * wa.x + a.y * wa.y + a.z * wa.z + a.w * wa.w +
              b.x * wb.x + b.y * wb.y + b.z * wb.z + b.w * wb.w;
    for (int off = 1; off < 64; off <<= 1) d += __shfl_xor(d, off, 64);
    if (lane == 0) vw[row] = d + *bvs;  // bvs folded in HERE (only here)
}

// ---------------- Q,K GEMM — m97-style 128x128 LDS-staged tiles (r10) --------
__global__ __launch_bounds__(256, 2) void qkv_kernel(
    const unsigned short* __restrict__ xb, const unsigned short* __restrict__ wb,
    const float* __restrict__ bq, const float* __restrict__ bk,
    unsigned short* __restrict__ qo, unsigned short* __restrict__ ko) {
    __shared__ unsigned short alds[128 * 32];  // 8 KB
    __shared__ unsigned short blds[128 * 32];  // 8 KB
    const int g = blockIdx.x;
    const int xcd = g & 7, t2 = g >> 3;
    const int colBlk = t2 & 3, rowGrp = t2 >> 2;
    const int rowBlk = rowGrp * 8 + xcd;
    const int tid = threadIdx.x;
    const int wave = tid >> 6, lane = tid & 63, quad = lane >> 4, l16 = lane & 15;
    const int wr = wave >> 1, wc = wave & 1;
    const int row0 = rowBlk * 128, col0 = colBlk * 128;

    floatx4 acc[4][4];
#pragma unroll
    for (int i = 0; i < 4; ++i)
#pragma unroll
        for (int j = 0; j < 4; ++j) acc[i][j] = (floatx4){0.f, 0.f, 0.f, 0.f};

    const unsigned short* ag = xb + (size_t)(row0 + (tid >> 2)) * DIN_ + (tid & 3) * 8;
    const unsigned short* bg = wb + (size_t)(col0 + (tid >> 2)) * DIN_ + (tid & 3) * 8;
    unsigned short* alw0 = alds + (size_t)(wave * 64) * 8;
    unsigned short* alw1 = alds + (size_t)(256 + wave * 64) * 8;
    unsigned short* blw0 = blds + (size_t)(wave * 64) * 8;
    unsigned short* blw1 = blds + (size_t)(256 + wave * 64) * 8;

#pragma unroll 1
    for (int kc = 0; kc < DIN_; kc += 32) {
        __syncthreads();
        load_lds16(ag + kc, alw0);
        load_lds16(ag + (size_t)64 * DIN_ + kc, alw1);
        load_lds16(bg + kc, blw0);
        load_lds16(bg + (size_t)64 * DIN_ + kc, blw1);
        __syncthreads();
        short8 af[4], bf[4];
#pragma unroll
        for (int f = 0; f < 4; ++f) {
            af[f] = *(const short8*)&alds[(size_t)(wr * 64 + f * 16 + l16) * 32 + quad * 8];
            bf[f] = *(const short8*)&blds[(size_t)(wc * 64 + f * 16 + l16) * 32 + quad * 8];
        }
#pragma unroll
        for (int i = 0; i < 4; ++i)
#pragma unroll
            for (int j = 0; j < 4; ++j)
                acc[i][j] = __builtin_amdgcn_mfma_f32_16x16x32_bf16(af[i], bf[j], acc[i][j], 0, 0, 0);
    }

#pragma unroll
    for (int j = 0; j < 4; ++j) {
        int col = col0 + wc * 64 + j * 16 + l16;
        unsigned short* dst = (col < 256) ? qo : ko;
        float bias = (col < 256) ? bq[col] : bk[col - 256];
        int c = col & 255;
#pragma unroll
        for (int i = 0; i < 4; ++i)
#pragma unroll
            for (int r = 0; r < 4; ++r) {
                int row = row0 + wr * 64 + i * 16 + quad * 4 + r;
                dst[(size_t)row * DOUT_ + c] = f2b(acc[i][j][r] + bias);
            }
    }
}

// ---------------- gated flash attention — r11 pipeline, vmcnt-ordered --------
// grid 256: b = g&7 (XCD-affine), rblk = g>>3 -> 64 q-rows/block, 8 waves.
// Exact r11 structure (64 rows, reuse 4, runtime dbuf parity, per-chunk
// address recompute, unroll 1 — r13's srcp array + unroll 2 spilled).
// FIX vs r11: vmcnt is a single in-order counter; r11 loaded prb/vwb AFTER
// issuing the prefetch DMAs, so the exp section's wait on those scalars
// drained the whole DMA queue every chunk (silent re-serialization). Now the
// scalar loads for chunk j+1 are issued BEFORE its DMAs and consumed one
// chunk later: every wait targets loads a full chunk old; DMAs stay in
// flight. +3 VGPRs only. 0.2 gate factor folded into prn5 (register-neutral).
__global__ __launch_bounds__(512, 2) void attn_kernel(
    const unsigned short* __restrict__ q, const unsigned short* __restrict__ k,
    const float* __restrict__ vw, const int* __restrict__ pr,
    const float* __restrict__ rank_emb, const float* __restrict__ rank_w,
    const float* __restrict__ bs, float* __restrict__ out) {
    const int g = blockIdx.x;
    const int b = g & 7, rblk = g >> 3;
    const int tid = threadIdx.x, wave = tid >> 6, lane = tid & 63;
    const int quad = lane >> 4, l16 = lane & 15;
    const int n0 = rblk * 64;
    const int sw = l16 & 7;

    __shared__ unsigned short klds[2][8][4096];  // [parity][wave][8KB]
    __shared__ float gtab[NBUCK];
    __shared__ float lL[8][64], wdL[8][64];

    if (tid < NBUCK)  // scale * log2e folded in
        gtab[tid] = 0.0625f * 1.44269504f / (1.f + __expf(-rank_w[0] * rank_emb[tid]));
    __syncthreads();  // gtab visibility — the only pre-loop barrier

    const unsigned short* qb = q + (size_t)b * N_ * DOUT_;
    const unsigned short* kb = k + (size_t)b * N_ * DOUT_;
    const float* vwb = vw + b * N_;
    const int* prb = pr + b * N_;

    short8 qf[4][8];
#pragma unroll
    for (int a = 0; a < 4; ++a)
#pragma unroll
        for (int c = 0; c < 8; ++c)
            qf[a][c] = *(const short8*)(qb + (size_t)(n0 + a * 16 + l16) * DOUT_ + c * 32 + quad * 8);

    float prn5[4][4];
#pragma unroll
    for (int a = 0; a < 4; ++a)
#pragma unroll
        for (int r = 0; r < 4; ++r)
            prn5[a][r] = (float)prb[n0 + a * 16 + quad * 4 + r] * 0.2f;

    float lacc[4][4], wacc[4][4];
#pragma unroll
    for (int a = 0; a < 4; ++a)
#pragma unroll
        for (int r = 0; r < 4; ++r) { lacc[a][r] = 0.f; wacc[a][r] = 0.f; }

    // per-wave private staging (r11 geometry): 8 issues/lane per 8KB chunk.
    const int srow = lane >> 5;
    const int spos = lane & 31;
    const unsigned short* kwb = kb + (size_t)(wave * 16) * DOUT_;
    unsigned short* buf0 = &klds[0][wave][0];
    unsigned short* buf1 = &klds[1][wave][0];
    const int colbase = wave * 16 + l16;

    // scalar prefetch for chunk 0 — ordered BEFORE any DMA issue
    int   prm_raw = prb[colbase];
    float vwv_cur = vwb[colbase];

    // prologue: stage chunk 0
#pragma unroll
    for (int i = 0; i < 8; ++i) {
        int row = i * 2 + srow;
        int gseg = spos ^ (row & 7);
        load_lds16(kwb + (size_t)row * DOUT_ + gseg * 8, buf0 + i * 512);
    }

#pragma unroll 1
    for (int j = 0; j < 16; ++j) {
        unsigned short* bufc = (j & 1) ? buf1 : buf0;
        unsigned short* bufn = (j & 1) ? buf0 : buf1;

        // ---- fragment reads + MFMA (waits only this wave's chunk-j DMAs,
        //      issued a full chunk ago) ----------------------------------------
        floatx4 s[4];
#pragma unroll
        for (int a = 0; a < 4; ++a) s[a] = (floatx4){0.f, 0.f, 0.f, 0.f};
#pragma unroll
        for (int c = 0; c < 8; ++c) {
            int seg = (quad + 4 * c) ^ sw;
            short8 kf = *(const short8*)&bufc[((size_t)l16 * 32 + seg) * 8];
            s[0] = __builtin_amdgcn_mfma_f32_16x16x32_bf16(qf[0][c], kf, s[0], 0, 0, 0);
            s[1] = __builtin_amdgcn_mfma_f32_16x16x32_bf16(qf[1][c], kf, s[1], 0, 0, 0);
            s[2] = __builtin_amdgcn_mfma_f32_16x16x32_bf16(qf[2][c], kf, s[2], 0, 0, 0);
            s[3] = __builtin_amdgcn_mfma_f32_16x16x32_bf16(qf[3][c], kf, s[3], 0, 0, 0);
        }
        // ---- scalar loads for chunk j+1 FIRST (so the later DMAs are newer
        //      in the vmcnt queue; consumed next chunk -> wait is ~free) ------
        int nxtcol = ((j < 15) ? (j + 1) * 128 : j * 128) + colbase;
        int   prm_nxt = prb[nxtcol];
        float vwv_nxt = vwb[nxtcol];
        // ---- prefetch chunk j+1 DMAs (stay in flight through the exp) ------
        if (j < 15) {
            const unsigned short* src = kwb + (size_t)(j + 1) * 128 * DOUT_;
#pragma unroll
            for (int i = 0; i < 8; ++i) {
                int row = i * 2 + srow;
                int gseg = spos ^ (row & 7);
                load_lds16(src + (size_t)row * DOUT_ + gseg * 8, bufn + i * 512);
            }
        }
        // ---- gate + exp accumulation (uses chunk-j scalars loaded last
        //      chunk — no dependency on the DMAs just issued) ----------------
        float prm5 = (float)prm_raw * 0.2f;
#pragma unroll
        for (int a = 0; a < 4; ++a)
#pragma unroll
            for (int r = 0; r < 4; ++r) {
                float d5 = fabsf(prn5[a][r] - prm5);
                int idx = (int)fminf(d5, 19.0f);
                float p = exp2f(s[a][r] * gtab[idx]);
                lacc[a][r] += p;
                wacc[a][r] += p * vwv_cur;
            }
        prm_raw = prm_nxt;
        vwv_cur = vwv_nxt;
    }

    // merge partial (l, wd) across the 16 column-lanes
#pragma unroll
    for (int off = 1; off < 16; off <<= 1) {
#pragma unroll
        for (int a = 0; a < 4; ++a)
#pragma unroll
            for (int r = 0; r < 4; ++r) {
                lacc[a][r] += __shfl_xor(lacc[a][r], off, 64);
                wacc[a][r] += __shfl_xor(wacc[a][r], off, 64);
            }
    }
    if (l16 == 0) {
#pragma unroll
        for (int a = 0; a < 4; ++a)
#pragma unroll
            for (int r = 0; r < 4; ++r) {
                int row = a * 16 + quad * 4 + r;
                lL[wave][row]  = lacc[a][r];
                wdL[wave][row] = wacc[a][r];
            }
    }
    __syncthreads();
    if (tid < 64) {
        float l = 0.f, wd = 0.f;
#pragma unroll
        for (int s2 = 0; s2 < 8; ++s2) { l += lL[s2][tid]; wd += wdL[s2][tid]; }
        float logit = wd / l + bs[0];   // bvs already inside vw
        out[(size_t)b * N_ + n0 + tid] = 1.f / (1.f + __expf(-logit));
    }
}

// ---------------- launch ----------------
extern "C" void kernel_launch(void* const* d_in, const int* in_sizes, int n_in,
                              void* d_out, int out_size, void* d_ws, size_t ws_size,
                              hipStream_t stream) {
    const float* x   = (const float*)d_in[0];
    const int*   pr  = (const int*)d_in[1];
    const float* Wq  = (const float*)d_in[2];
    const float* bq  = (const float*)d_in[3];
    const float* Wk  = (const float*)d_in[4];
    const float* bk  = (const float*)d_in[5];
    const float* Wv  = (const float*)d_in[6];
    const float* bv  = (const float*)d_in[7];
    const float* Ws  = (const float*)d_in[8];
    const float* bs  = (const float*)d_in[9];
    const float* remb = (const float*)d_in[10];
    const float* rw   = (const float*)d_in[11];
    float* out = (float*)d_out;

    char* ws = (char*)d_ws;
    unsigned short* xb  = (unsigned short*)ws;                    // 16,777,216 B
    unsigned short* wb  = (unsigned short*)(ws + 16777216);       //    524,288 B
    unsigned short* q   = (unsigned short*)(ws + 17301504);       //  8,388,608 B
    unsigned short* kk  = (unsigned short*)(ws + 25690112);       //  8,388,608 B
    float*          vwp = (float*)(ws + 34078720);                //     65,536 B
    float*          wvs = (float*)(ws + 34144256);                //      2,048 B
    float*          bvs = (float*)(ws + 34146304);                //          4 B

    hipLaunchKernelGGL(prep_kernel, dim3(132), dim3(256), 0, stream,
                       Wq, Wk, Wv, Ws, bv, wb, wvs, bvs);
    hipLaunchKernelGGL(cvt_x_kernel, dim3(4096), dim3(256), 0, stream, x, wvs, bvs, xb, vwp);
    hipLaunchKernelGGL(qkv_kernel, dim3(512), dim3(256), 0, stream,
                       xb, wb, bq, bk, q, kk);
    hipLaunchKernelGGL(attn_kernel, dim3(256), dim3(512), 0, stream,
                       q, kk, vwp, pr, remb, rw, bs, out);
}